// Round 1
// baseline (1293.139 us; speedup 1.0000x reference)
//
#include <hip/hip_runtime.h>
#include <cstdint>
#include <cstddef>

#define NB 2
#define NN 4096
#define ND 256

typedef __attribute__((ext_vector_type(8))) _Float16 half8;
typedef __attribute__((ext_vector_type(4))) _Float16 half4;
typedef __attribute__((ext_vector_type(4))) float f32x4;

__device__ __forceinline__ f32x4 mfma_16x16x32(half8 a, half8 b, f32x4 c) {
    return __builtin_amdgcn_mfma_f32_16x16x32_f16(a, b, c, 0, 0, 0);
}

// ---------------- conversions ----------------
__global__ __launch_bounds__(256) void k_cvt_h(const float* __restrict__ h,
                                               _Float16* __restrict__ h16) {
    const int i = blockIdx.x * 256 + threadIdx.x;            // i indexes groups of 4
    f32x4 v = ((const f32x4*)h)[i];
    half4 o;
    o[0] = (_Float16)v[0]; o[1] = (_Float16)v[1];
    o[2] = (_Float16)v[2]; o[3] = (_Float16)v[3];
    ((half4*)h16)[i] = o;
}

// transpose + convert the four 256x256 weights: T[j][k] = W[k][j]
__global__ __launch_bounds__(256) void k_wt(const float* __restrict__ W0, const float* __restrict__ W1,
                                            const float* __restrict__ W2, const float* __restrict__ W3,
                                            _Float16* __restrict__ T0, _Float16* __restrict__ T1,
                                            _Float16* __restrict__ T2, _Float16* __restrict__ T3) {
    const int m = blockIdx.y;
    const float* W = m == 0 ? W0 : m == 1 ? W1 : m == 2 ? W2 : W3;
    _Float16* T    = m == 0 ? T0 : m == 1 ? T1 : m == 2 ? T2 : T3;
    const int k = blockIdx.x, j = threadIdx.x;
    T[j * ND + k] = (_Float16)W[k * ND + j];
}

// ---------------- GEMM core: 64 rows/block (4 waves x 16 rows), 256 cols, K=256 ----
// A row-major [rows][256] f16, Bt [col][k] f16 (i.e. B transposed).
// Fragment layouts (v_mfma_f32_16x16x32_f16):
//   A: lane holds A[l&15][(l>>4)*8+e]   B: lane holds B[(l>>4)*8+e][l&15]
//   C/D: lane holds C[(l>>4)*4+r][l&15]
__device__ __forceinline__ void gemm_core(const _Float16* __restrict__ A,
                                          const _Float16* __restrict__ Bt,
                                          int row0, int l16, int lg, f32x4 acc[16]) {
    #pragma unroll
    for (int i = 0; i < 16; ++i) acc[i] = (f32x4)0.0f;
    #pragma unroll
    for (int ks = 0; ks < 8; ++ks) {
        half8 a = *(const half8*)(A + (size_t)(row0 + l16) * ND + ks * 32 + lg * 8);
        #pragma unroll
        for (int ct = 0; ct < 16; ++ct) {
            half8 b = *(const half8*)(Bt + (size_t)(ct * 16 + l16) * ND + ks * 32 + lg * 8);
            acc[ct] = mfma_16x16x32(a, b, acc[ct]);
        }
    }
}

// mode 0: z_l -> zn (row-normalized) f16
// mode 1: z_g -> zg f16 + sq (row |z|^2) f32
// mode 2: v   -> v16 f16
__global__ __launch_bounds__(256) void k_proj(const _Float16* __restrict__ h16,
                                              const _Float16* __restrict__ Wlt,
                                              const _Float16* __restrict__ Wgt,
                                              const _Float16* __restrict__ Wvt,
                                              _Float16* __restrict__ zn,
                                              _Float16* __restrict__ zg,
                                              _Float16* __restrict__ v16,
                                              float* __restrict__ sq) {
    const int mode = blockIdx.y;
    const _Float16* Bt = mode == 0 ? Wlt : mode == 1 ? Wgt : Wvt;
    _Float16* o16      = mode == 0 ? zn  : mode == 1 ? zg  : v16;
    const int w = threadIdx.x >> 6, l = threadIdx.x & 63;
    const int l16 = l & 15, lg = l >> 4;
    const int row0 = blockIdx.x * 64 + w * 16;
    f32x4 acc[16];
    gemm_core(h16, Bt, row0, l16, lg, acc);

    if (mode == 2) {
        #pragma unroll
        for (int ct = 0; ct < 16; ++ct)
            #pragma unroll
            for (int r = 0; r < 4; ++r)
                o16[(size_t)(row0 + lg * 4 + r) * ND + ct * 16 + l16] = (_Float16)acc[ct][r];
        return;
    }
    float n2[4] = {0.f, 0.f, 0.f, 0.f};
    #pragma unroll
    for (int ct = 0; ct < 16; ++ct)
        #pragma unroll
        for (int r = 0; r < 4; ++r) n2[r] += acc[ct][r] * acc[ct][r];
    #pragma unroll
    for (int m = 1; m < 16; m <<= 1) {
        #pragma unroll
        for (int r = 0; r < 4; ++r) n2[r] += __shfl_xor(n2[r], m);
    }
    if (mode == 0) {
        float ri[4];
        #pragma unroll
        for (int r = 0; r < 4; ++r) ri[r] = 1.0f / fmaxf(sqrtf(n2[r]), 1e-8f);
        #pragma unroll
        for (int ct = 0; ct < 16; ++ct)
            #pragma unroll
            for (int r = 0; r < 4; ++r)
                o16[(size_t)(row0 + lg * 4 + r) * ND + ct * 16 + l16] =
                    (_Float16)(acc[ct][r] * ri[r]);
    } else {
        #pragma unroll
        for (int ct = 0; ct < 16; ++ct)
            #pragma unroll
            for (int r = 0; r < 4; ++r)
                o16[(size_t)(row0 + lg * 4 + r) * ND + ct * 16 + l16] = (_Float16)acc[ct][r];
        if (l16 == 0) {
            #pragma unroll
            for (int r = 0; r < 4; ++r) sq[row0 + lg * 4 + r] = n2[r];
        }
    }
}

// v16 [b][n][d] -> vT [b][d][n]
__global__ __launch_bounds__(256) void k_tr(const _Float16* __restrict__ v16,
                                            _Float16* __restrict__ vT) {
    __shared__ _Float16 t[64][72];
    const int b = blockIdx.z, n0 = blockIdx.x * 64, d0 = blockIdx.y * 64;
    const int tj = threadIdx.x & 63, ti = threadIdx.x >> 6;
    #pragma unroll
    for (int i = 0; i < 16; ++i)
        t[ti + i * 4][tj] = v16[(size_t)(b * NN + n0 + ti + i * 4) * ND + d0 + tj];
    __syncthreads();
    #pragma unroll
    for (int i = 0; i < 16; ++i)
        vT[(size_t)(b * ND + d0 + ti + i * 4) * NN + n0 + tj] = t[tj][ti + i * 4];
}

// ---------------- fused dual-adjacency flash kernel ----------------
// Block: 4 waves, 64 q-rows (wave w owns q0..q0+15). Loops key tiles of 64.
__global__ __launch_bounds__(256) void k_fused(const _Float16* __restrict__ zn,
                                               const _Float16* __restrict__ zg,
                                               const _Float16* __restrict__ vT,
                                               const float* __restrict__ sqg,
                                               _Float16* __restrict__ ot) {
    const int b = blockIdx.y;
    const int t = 63 - blockIdx.x;               // big tiles dispatched first
    const int w = threadIdx.x >> 6, l = threadIdx.x & 63;
    const int l16 = l & 15, lg = l >> 4;
    const int q0 = t * 64 + w * 16;

    __shared__ _Float16 P[4][2][16][72];         // per-wave private P staging (+8 pad)

    const _Float16* znb = zn + (size_t)b * NN * ND;
    const _Float16* zgb = zg + (size_t)b * NN * ND;
    const _Float16* vTb = vT + (size_t)b * ND * NN;
    const float*    sqb = sqg + (size_t)b * NN;

    f32x4 accl[16], accg[16];
    #pragma unroll
    for (int i = 0; i < 16; ++i) { accl[i] = (f32x4)0.0f; accg[i] = (f32x4)0.0f; }
    f32x4 degl = (f32x4)0.0f, degg = (f32x4)0.0f;
    f32x4 sqq = *(const f32x4*)(sqb + q0 + lg * 4);

    // hoisted q-side A-fragments (invariant over key tiles)
    half8 aql[8], aqg[8];
    #pragma unroll
    for (int ks = 0; ks < 8; ++ks) {
        aql[ks] = *(const half8*)(znb + (size_t)(q0 + l16) * ND + ks * 32 + lg * 8);
        aqg[ks] = *(const half8*)(zgb + (size_t)(q0 + l16) * ND + ks * 32 + lg * 8);
    }

    for (int kt = 0; kt <= t; ++kt) {
        const int k0 = kt * 64;
        // ---- scores: S[q][key] for 4 key sub-tiles of 16
        #pragma unroll
        for (int kk = 0; kk < 4; ++kk) {
            f32x4 sl = (f32x4)0.0f, sg = (f32x4)0.0f;
            const int krow = k0 + kk * 16 + l16;
            #pragma unroll
            for (int ks = 0; ks < 8; ++ks) {
                half8 bl = *(const half8*)(znb + (size_t)krow * ND + ks * 32 + lg * 8);
                sl = mfma_16x16x32(aql[ks], bl, sl);
                half8 bg = *(const half8*)(zgb + (size_t)krow * ND + ks * 32 + lg * 8);
                sg = mfma_16x16x32(aqg[ks], bg, sg);
            }
            const float sqk = sqb[krow];
            #pragma unroll
            for (int r = 0; r < 4; ++r) {
                const int q = q0 + lg * 4 + r;
                const bool msk = krow < q;                     // causal + zero-diag
                float al = msk ? fmaxf(sl[r], 0.0f) : 0.0f;    // cosine adjacency
                float d2 = fmaxf(sqq[r] + sqk - 2.0f * sg[r], 0.0f);
                float ag = msk ? __expf(-0.5f * d2) : 0.0f;    // RBF adjacency (sigma=1)
                degl[r] += al; degg[r] += ag;
                P[w][0][lg * 4 + r][kk * 16 + l16] = (_Float16)al;
                P[w][1][lg * 4 + r][kk * 16 + l16] = (_Float16)ag;
            }
        }
        // ---- PV: acc[q][d] += P[q][key] * V[key][d], K=64 via 2 k-steps
        #pragma unroll
        for (int ks2 = 0; ks2 < 2; ++ks2) {
            half8 pal = *(const half8*)&P[w][0][l16][ks2 * 32 + lg * 8];
            half8 pag = *(const half8*)&P[w][1][l16][ks2 * 32 + lg * 8];
            #pragma unroll
            for (int dt = 0; dt < 16; ++dt) {
                half8 vb = *(const half8*)(vTb + (size_t)(dt * 16 + l16) * NN + k0 + ks2 * 32 + lg * 8);
                accl[dt] = mfma_16x16x32(pal, vb, accl[dt]);
                accg[dt] = mfma_16x16x32(pag, vb, accg[dt]);
            }
        }
    }

    // reduce degrees across the 16 key-lanes of each lane-group
    #pragma unroll
    for (int m = 1; m < 16; m <<= 1) {
        #pragma unroll
        for (int r = 0; r < 4; ++r) {
            degl[r] += __shfl_xor(degl[r], m);
            degg[r] += __shfl_xor(degg[r], m);
        }
    }
    f32x4 rl, rg;
    #pragma unroll
    for (int r = 0; r < 4; ++r) {
        rl[r] = 0.9f / fmaxf(degl[r], 1e-8f);    // w_l = 1 - T_WAKE
        rg[r] = 0.1f / fmaxf(degg[r], 1e-8f);    // w_g = T_WAKE
    }
    #pragma unroll
    for (int dt = 0; dt < 16; ++dt)
        #pragma unroll
        for (int r = 0; r < 4; ++r)
            ot[(size_t)(b * NN + q0 + lg * 4 + r) * ND + dt * 16 + l16] =
                (_Float16)(accl[dt][r] * rl[r] + accg[dt][r] * rg[r]);
}

// ---------------- final @ Wo ----------------
__global__ __launch_bounds__(256) void k_out(const _Float16* __restrict__ ot,
                                             const _Float16* __restrict__ Wot,
                                             float* __restrict__ out) {
    const int w = threadIdx.x >> 6, l = threadIdx.x & 63;
    const int l16 = l & 15, lg = l >> 4;
    const int row0 = blockIdx.x * 64 + w * 16;
    f32x4 acc[16];
    gemm_core(ot, Wot, row0, l16, lg, acc);
    #pragma unroll
    for (int ct = 0; ct < 16; ++ct)
        #pragma unroll
        for (int r = 0; r < 4; ++r)
            out[(size_t)(row0 + lg * 4 + r) * ND + ct * 16 + l16] = acc[ct][r];
}

extern "C" void kernel_launch(void* const* d_in, const int* in_sizes, int n_in,
                              void* d_out, int out_size, void* d_ws, size_t ws_size,
                              hipStream_t stream) {
    const float* h  = (const float*)d_in[0];
    // d_in[1] = causal_mask (unused; causality is structural)
    const float* Wl = (const float*)d_in[2];
    const float* Wg = (const float*)d_in[3];
    const float* Wv = (const float*)d_in[4];
    const float* Wo = (const float*)d_in[5];
    float* out = (float*)d_out;

    uint8_t* base = (uint8_t*)d_ws;
    size_t off = 0;
    auto alloc = [&](size_t bytes) -> void* {
        void* r = base + off;
        off = (off + bytes + 255) & ~(size_t)255;
        return r;
    };
    const size_t bnd = (size_t)NB * NN * ND;
    _Float16* h16 = (_Float16*)alloc(bnd * 2);
    _Float16* Wlt = (_Float16*)alloc(ND * ND * 2);
    _Float16* Wgt = (_Float16*)alloc(ND * ND * 2);
    _Float16* Wvt = (_Float16*)alloc(ND * ND * 2);
    _Float16* Wot = (_Float16*)alloc(ND * ND * 2);
    _Float16* zn  = (_Float16*)alloc(bnd * 2);
    _Float16* zg  = (_Float16*)alloc(bnd * 2);
    _Float16* v16 = (_Float16*)alloc(bnd * 2);
    _Float16* vT  = (_Float16*)alloc(bnd * 2);
    _Float16* ot  = (_Float16*)alloc(bnd * 2);
    float*    sq  = (float*)alloc((size_t)NB * NN * 4);

    k_cvt_h<<<bnd / 4 / 256, 256, 0, stream>>>(h, h16);
    k_wt<<<dim3(ND, 4), 256, 0, stream>>>(Wl, Wg, Wv, Wo, Wlt, Wgt, Wvt, Wot);
    k_proj<<<dim3(NB * NN / 64, 3), 256, 0, stream>>>(h16, Wlt, Wgt, Wvt, zn, zg, v16, sq);
    k_tr<<<dim3(NN / 64, ND / 64, NB), 256, 0, stream>>>(v16, vT);
    k_fused<<<dim3(NN / 64, NB), 256, 0, stream>>>(zn, zg, vT, sq, ot);
    k_out<<<NB * NN / 64, 256, 0, stream>>>(ot, Wot, out);
}

// Round 2
// 455.860 us; speedup vs baseline: 2.8367x; 2.8367x over previous
//
#include <hip/hip_runtime.h>
#include <cstdint>
#include <cstddef>

#define NB 2
#define NN 4096
#define ND 256
#define SLOT_F 32896   // floats per partial slot: 2*64*256 acc + 2*64 deg

typedef __attribute__((ext_vector_type(8))) _Float16 half8;
typedef __attribute__((ext_vector_type(4))) _Float16 half4;
typedef __attribute__((ext_vector_type(4))) float f32x4;

using gas_ptr = const __attribute__((address_space(1))) void*;
using las_ptr = __attribute__((address_space(3))) void*;

__device__ __forceinline__ f32x4 mfma_16x16x32(half8 a, half8 b, f32x4 c) {
    return __builtin_amdgcn_mfma_f32_16x16x32_f16(a, b, c, 0, 0, 0);
}

// ---------------- conversions ----------------
__global__ __launch_bounds__(256) void k_cvt_h(const float* __restrict__ h,
                                               _Float16* __restrict__ h16) {
    const int i = blockIdx.x * 256 + threadIdx.x;
    f32x4 v = ((const f32x4*)h)[i];
    half4 o;
    o[0] = (_Float16)v[0]; o[1] = (_Float16)v[1];
    o[2] = (_Float16)v[2]; o[3] = (_Float16)v[3];
    ((half4*)h16)[i] = o;
}

__global__ __launch_bounds__(256) void k_wt(const float* __restrict__ W0, const float* __restrict__ W1,
                                            const float* __restrict__ W2, const float* __restrict__ W3,
                                            _Float16* __restrict__ T0, _Float16* __restrict__ T1,
                                            _Float16* __restrict__ T2, _Float16* __restrict__ T3) {
    const int m = blockIdx.y;
    const float* W = m == 0 ? W0 : m == 1 ? W1 : m == 2 ? W2 : W3;
    _Float16* T    = m == 0 ? T0 : m == 1 ? T1 : m == 2 ? T2 : T3;
    const int k = blockIdx.x, j = threadIdx.x;
    T[j * ND + k] = (_Float16)W[k * ND + j];
}

// ---------------- GEMM core (projections / output) ----------------
__device__ __forceinline__ void gemm_core(const _Float16* __restrict__ A,
                                          const _Float16* __restrict__ Bt,
                                          int row0, int l16, int lg, f32x4 acc[16]) {
    #pragma unroll
    for (int i = 0; i < 16; ++i) acc[i] = (f32x4)0.0f;
    #pragma unroll
    for (int ks = 0; ks < 8; ++ks) {
        half8 a = *(const half8*)(A + (size_t)(row0 + l16) * ND + ks * 32 + lg * 8);
        #pragma unroll
        for (int ct = 0; ct < 16; ++ct) {
            half8 b = *(const half8*)(Bt + (size_t)(ct * 16 + l16) * ND + ks * 32 + lg * 8);
            acc[ct] = mfma_16x16x32(a, b, acc[ct]);
        }
    }
}

__global__ __launch_bounds__(256) void k_proj(const _Float16* __restrict__ h16,
                                              const _Float16* __restrict__ Wlt,
                                              const _Float16* __restrict__ Wgt,
                                              const _Float16* __restrict__ Wvt,
                                              _Float16* __restrict__ zn,
                                              _Float16* __restrict__ zg,
                                              _Float16* __restrict__ v16,
                                              float* __restrict__ sq) {
    const int mode = blockIdx.y;
    const _Float16* Bt = mode == 0 ? Wlt : mode == 1 ? Wgt : Wvt;
    _Float16* o16      = mode == 0 ? zn  : mode == 1 ? zg  : v16;
    const int w = threadIdx.x >> 6, l = threadIdx.x & 63;
    const int l16 = l & 15, lg = l >> 4;
    const int row0 = blockIdx.x * 64 + w * 16;
    f32x4 acc[16];
    gemm_core(h16, Bt, row0, l16, lg, acc);

    if (mode == 2) {
        #pragma unroll
        for (int ct = 0; ct < 16; ++ct)
            #pragma unroll
            for (int r = 0; r < 4; ++r)
                o16[(size_t)(row0 + lg * 4 + r) * ND + ct * 16 + l16] = (_Float16)acc[ct][r];
        return;
    }
    float n2[4] = {0.f, 0.f, 0.f, 0.f};
    #pragma unroll
    for (int ct = 0; ct < 16; ++ct)
        #pragma unroll
        for (int r = 0; r < 4; ++r) n2[r] += acc[ct][r] * acc[ct][r];
    #pragma unroll
    for (int m = 1; m < 16; m <<= 1) {
        #pragma unroll
        for (int r = 0; r < 4; ++r) n2[r] += __shfl_xor(n2[r], m);
    }
    if (mode == 0) {
        float ri[4];
        #pragma unroll
        for (int r = 0; r < 4; ++r) ri[r] = 1.0f / fmaxf(sqrtf(n2[r]), 1e-8f);
        #pragma unroll
        for (int ct = 0; ct < 16; ++ct)
            #pragma unroll
            for (int r = 0; r < 4; ++r)
                o16[(size_t)(row0 + lg * 4 + r) * ND + ct * 16 + l16] =
                    (_Float16)(acc[ct][r] * ri[r]);
    } else {
        #pragma unroll
        for (int ct = 0; ct < 16; ++ct)
            #pragma unroll
            for (int r = 0; r < 4; ++r)
                o16[(size_t)(row0 + lg * 4 + r) * ND + ct * 16 + l16] = (_Float16)acc[ct][r];
        if (l16 == 0) {
            #pragma unroll
            for (int r = 0; r < 4; ++r) sq[row0 + lg * 4 + r] = n2[r];
        }
    }
}

// v16 [b][n][d] -> vT [b][d][n]
__global__ __launch_bounds__(256) void k_tr(const _Float16* __restrict__ v16,
                                            _Float16* __restrict__ vT) {
    __shared__ _Float16 t[64][72];
    const int b = blockIdx.z, n0 = blockIdx.x * 64, d0 = blockIdx.y * 64;
    const int tj = threadIdx.x & 63, ti = threadIdx.x >> 6;
    #pragma unroll
    for (int i = 0; i < 16; ++i)
        t[ti + i * 4][tj] = v16[(size_t)(b * NN + n0 + ti + i * 4) * ND + d0 + tj];
    __syncthreads();
    #pragma unroll
    for (int i = 0; i < 16; ++i)
        vT[(size_t)(b * ND + d0 + ti + i * 4) * NN + n0 + tj] = t[tj][ti + i * 4];
}

// ---------------- fused dual-adjacency pass with split-K ----------------
// Block: 4 waves, q-tile of 64 rows, key chunk of `len` 32-key tiles.
// Scores: wave w owns q rows [q0w, q0w+16). PV: wave w owns all 64 q x 64 d.
// Keys staged in LDS (XOR-swizzled), P shared in LDS (XOR-swizzled),
// V^T fragments register-prefetched one tile ahead.
__global__ __launch_bounds__(256, 2) void k_fused_split(
        const _Float16* __restrict__ zn, const _Float16* __restrict__ zg,
        const _Float16* __restrict__ vT, const float* __restrict__ sqg,
        float* __restrict__ part, int nchunk) {
    const int item = blockIdx.x;
    const int t = 63 - item / nchunk;        // big tiles dispatched first
    const int c = item % nchunk;
    const int b = blockIdx.y;
    const int ntt = 2 * (t + 1);             // total 32-key tiles for this q-tile
    const int len = (ntt + nchunk - 1) / nchunk;
    const int kt0 = c * len;
    const int ktE = (kt0 + len < ntt) ? (kt0 + len) : ntt;
    if (kt0 >= ktE) return;

    const int w = threadIdx.x >> 6, lane = threadIdx.x & 63;
    const int l16 = lane & 15, lg = lane >> 4;

    __shared__ char keys[2][16384];          // [mat][row*512 ^ swz] 32 rows x 512B
    __shared__ char Pl[2][64 * 128];         // [adj][row*128 ^ swz] 64 rows x 128B (64B used)

    const char* znb = (const char*)(zn + (size_t)b * NN * ND);
    const char* zgb = (const char*)(zg + (size_t)b * NN * ND);
    const _Float16* vTb = vT + (size_t)b * ND * NN;
    const float*    sqb = sqg + (size_t)b * NN;

    const int q0w = t * 64 + w * 16;

    // hoisted q-side fragments
    half8 aql[8], aqg[8];
    #pragma unroll
    for (int ks = 0; ks < 8; ++ks) {
        aql[ks] = *(const half8*)(znb + (size_t)(q0w + l16) * 512 + ks * 64 + lg * 16);
        aqg[ks] = *(const half8*)(zgb + (size_t)(q0w + l16) * 512 + ks * 64 + lg * 16);
    }
    f32x4 sqq = *(const f32x4*)(sqb + q0w + lg * 4);

    f32x4 accl[4][4], accg[4][4];
    #pragma unroll
    for (int i = 0; i < 4; ++i)
        #pragma unroll
        for (int j = 0; j < 4; ++j) { accl[i][j] = (f32x4)0.f; accg[i][j] = (f32x4)0.f; }
    float degl[4] = {0.f, 0.f, 0.f, 0.f}, degg[4] = {0.f, 0.f, 0.f, 0.f};

    half8 vr[4];

    auto stage = [&](int kt_) {
        const size_t gk = (size_t)kt_ * 32 * 512;
        #pragma unroll
        for (int m = 0; m < 2; ++m) {
            const char* gb = (m ? zgb : znb) + gk;
            char* lb = &keys[m][0];
            #pragma unroll
            for (int i = 0; i < 4; ++i) {
                const int off = w * 4096 + i * 1024 + lane * 16;
                const int row = off >> 9, x = off & 511;
                __builtin_amdgcn_global_load_lds(
                    (gas_ptr)(gb + row * 512 + (x ^ ((row & 7) << 4))),
                    (las_ptr)(lb + w * 4096 + i * 1024), 16, 0, 0);
            }
        }
    };
    auto pref_v = [&](int kt_) {
        const int k0 = kt_ * 32;
        #pragma unroll
        for (int ds = 0; ds < 4; ++ds)
            vr[ds] = *(const half8*)(vTb + (size_t)(w * 64 + ds * 16 + l16) * NN + k0 + lg * 8);
    };

    stage(kt0);
    pref_v(kt0);
    __syncthreads();

    for (int kt = kt0; kt < ktE; ++kt) {
        const int k0 = kt * 32;
        // ---- scores (2 key sub-tiles of 16)
        #pragma unroll
        for (int kk = 0; kk < 2; ++kk) {
            f32x4 sl = (f32x4)0.f, sg = (f32x4)0.f;
            const int krl = kk * 16 + l16;
            const int swz = (krl & 7) << 4;
            #pragma unroll
            for (int ks = 0; ks < 8; ++ks) {
                const int cb = ks * 64 + lg * 16;
                half8 bl = *(const half8*)(&keys[0][0] + krl * 512 + (cb ^ swz));
                sl = mfma_16x16x32(aql[ks], bl, sl);
                half8 bg = *(const half8*)(&keys[1][0] + krl * 512 + (cb ^ swz));
                sg = mfma_16x16x32(aqg[ks], bg, sg);
            }
            const int krow = k0 + krl;
            const float sqk = sqb[krow];
            #pragma unroll
            for (int r = 0; r < 4; ++r) {
                const int q = q0w + lg * 4 + r;
                const bool msk = krow < q;                     // causal + zero-diag
                float al = msk ? fmaxf(sl[r], 0.f) : 0.f;
                float d2 = fmaxf(sqq[r] + sqk - 2.f * sg[r], 0.f);
                float ag = msk ? __expf(-0.5f * d2) : 0.f;
                degl[r] += al; degg[r] += ag;
                const int prow = w * 16 + lg * 4 + r;
                const int psw = (prow & 7) << 4;
                *(_Float16*)(&Pl[0][0] + prow * 128 + ((krl * 2) ^ psw)) = (_Float16)al;
                *(_Float16*)(&Pl[1][0] + prow * 128 + ((krl * 2) ^ psw)) = (_Float16)ag;
            }
        }
        __syncthreads();                       // P visible; key reads done
        if (kt + 1 < ktE) stage(kt + 1);       // overlaps PV (keys unused there)
        // ---- PV: wave w covers all 64 q rows x its 64 d cols
        #pragma unroll
        for (int qs = 0; qs < 4; ++qs) {
            const int prow = qs * 16 + l16;
            const int psw = (prow & 7) << 4;
            half8 pa = *(const half8*)(&Pl[0][0] + prow * 128 + ((lg * 16) ^ psw));
            half8 pb = *(const half8*)(&Pl[1][0] + prow * 128 + ((lg * 16) ^ psw));
            #pragma unroll
            for (int ds = 0; ds < 4; ++ds) {
                accl[qs][ds] = mfma_16x16x32(pa, vr[ds], accl[qs][ds]);
                accg[qs][ds] = mfma_16x16x32(pb, vr[ds], accg[qs][ds]);
            }
        }
        if (kt + 1 < ktE) pref_v(kt + 1);      // latency hides under next scores
        __syncthreads();                       // drains stage; P reads done
    }

    // ---- write partial accumulators + degrees
    float* slot = part + (size_t)((b * 64 + t) * nchunk + c) * SLOT_F;
    float* pl = slot;
    float* pg = slot + 16384;
    #pragma unroll
    for (int qs = 0; qs < 4; ++qs)
        #pragma unroll
        for (int ds = 0; ds < 4; ++ds)
            #pragma unroll
            for (int r = 0; r < 4; ++r) {
                const int row = qs * 16 + lg * 4 + r, col = w * 64 + ds * 16 + l16;
                pl[row * 256 + col] = accl[qs][ds][r];
                pg[row * 256 + col] = accg[qs][ds][r];
            }
    #pragma unroll
    for (int m = 1; m < 16; m <<= 1) {
        #pragma unroll
        for (int r = 0; r < 4; ++r) {
            degl[r] += __shfl_xor(degl[r], m);
            degg[r] += __shfl_xor(degg[r], m);
        }
    }
    if (l16 == 0) {
        #pragma unroll
        for (int r = 0; r < 4; ++r) {
            slot[32768 + w * 16 + lg * 4 + r] = degl[r];
            slot[32832 + w * 16 + lg * 4 + r] = degg[r];
        }
    }
}

// ---------------- combine partials: sum, normalize, emit ot (f16) ----------------
__global__ __launch_bounds__(256) void k_combine(const float* __restrict__ part,
                                                 _Float16* __restrict__ ot, int nchunk) {
    const int t = blockIdx.x, b = blockIdx.y;
    const int ntt = 2 * (t + 1);
    const int len = (ntt + nchunk - 1) / nchunk;
    const int nact = (ntt + len - 1) / len;
    const float* s0 = part + (size_t)((b * 64 + t) * nchunk) * SLOT_F;
    __shared__ float rl[64], rg[64];
    if (threadIdx.x < 64) {
        float dl = 0.f, dg = 0.f;
        for (int cc = 0; cc < nact; ++cc) {
            dl += s0[(size_t)cc * SLOT_F + 32768 + threadIdx.x];
            dg += s0[(size_t)cc * SLOT_F + 32832 + threadIdx.x];
        }
        rl[threadIdx.x] = 0.9f / fmaxf(dl, 1e-8f);     // w_l = 1 - T_WAKE
        rg[threadIdx.x] = 0.1f / fmaxf(dg, 1e-8f);     // w_g = T_WAKE
    }
    __syncthreads();
    for (int idx = threadIdx.x; idx < 16384; idx += 256) {
        const int row = idx >> 8;
        float sl = 0.f, sg = 0.f;
        for (int cc = 0; cc < nact; ++cc) {
            sl += s0[(size_t)cc * SLOT_F + idx];
            sg += s0[(size_t)cc * SLOT_F + 16384 + idx];
        }
        ot[(size_t)(b * NN + t * 64 + row) * ND + (idx & 255)] =
            (_Float16)(rl[row] * sl + rg[row] * sg);
    }
}

// ---------------- final @ Wo ----------------
__global__ __launch_bounds__(256) void k_out(const _Float16* __restrict__ ot,
                                             const _Float16* __restrict__ Wot,
                                             float* __restrict__ out) {
    const int w = threadIdx.x >> 6, l = threadIdx.x & 63;
    const int l16 = l & 15, lg = l >> 4;
    const int row0 = blockIdx.x * 64 + w * 16;
    f32x4 acc[16];
    gemm_core(ot, Wot, row0, l16, lg, acc);
    #pragma unroll
    for (int ct = 0; ct < 16; ++ct)
        #pragma unroll
        for (int r = 0; r < 4; ++r)
            out[(size_t)(row0 + lg * 4 + r) * ND + ct * 16 + l16] = acc[ct][r];
}

extern "C" void kernel_launch(void* const* d_in, const int* in_sizes, int n_in,
                              void* d_out, int out_size, void* d_ws, size_t ws_size,
                              hipStream_t stream) {
    const float* h  = (const float*)d_in[0];
    const float* Wl = (const float*)d_in[2];
    const float* Wg = (const float*)d_in[3];
    const float* Wv = (const float*)d_in[4];
    const float* Wo = (const float*)d_in[5];
    float* out = (float*)d_out;

    uint8_t* base = (uint8_t*)d_ws;
    size_t off = 0;
    auto alloc = [&](size_t bytes) -> void* {
        void* r = base + off;
        off = (off + bytes + 255) & ~(size_t)255;
        return r;
    };
    const size_t bnd = (size_t)NB * NN * ND;
    _Float16* h16 = (_Float16*)alloc(bnd * 2);
    _Float16* Wlt = (_Float16*)alloc(ND * ND * 2);
    _Float16* Wgt = (_Float16*)alloc(ND * ND * 2);
    _Float16* Wvt = (_Float16*)alloc(ND * ND * 2);
    _Float16* Wot = (_Float16*)alloc(ND * ND * 2);
    _Float16* zn  = (_Float16*)alloc(bnd * 2);
    _Float16* zg  = (_Float16*)alloc(bnd * 2);
    _Float16* v16 = (_Float16*)alloc(bnd * 2);
    _Float16* vT  = (_Float16*)alloc(bnd * 2);
    _Float16* ot  = (_Float16*)alloc(bnd * 2);
    float*    sq  = (float*)alloc((size_t)NB * NN * 4);

    // split-K partial buffer (adaptive to ws_size)
    int nchunk = 4;
    while (nchunk > 1 &&
           off + (size_t)NB * 64 * nchunk * SLOT_F * 4 > ws_size)
        nchunk >>= 1;
    float* part = (float*)alloc((size_t)NB * 64 * nchunk * SLOT_F * 4);

    k_cvt_h<<<bnd / 4 / 256, 256, 0, stream>>>(h, h16);
    k_wt<<<dim3(ND, 4), 256, 0, stream>>>(Wl, Wg, Wv, Wo, Wlt, Wgt, Wvt, Wot);
    k_proj<<<dim3(NB * NN / 64, 3), 256, 0, stream>>>(h16, Wlt, Wgt, Wvt, zn, zg, v16, sq);
    k_tr<<<dim3(NN / 64, ND / 64, NB), 256, 0, stream>>>(v16, vT);
    k_fused_split<<<dim3(64 * nchunk, NB), 256, 0, stream>>>(zn, zg, vT, sq, part, nchunk);
    k_combine<<<dim3(NN / 64, NB), 256, 0, stream>>>(part, ot, nchunk);
    k_out<<<NB * NN / 64, 256, 0, stream>>>(ot, Wot, out);
}

// Round 3
// 234.871 us; speedup vs baseline: 5.5057x; 1.9409x over previous
//
#include <hip/hip_runtime.h>
#include <cstdint>
#include <cstddef>

#define NB 2
#define NN 4096
#define ND 256
#define SLOT_B 132096   // bytes/partial slot: f16 accl[128][256] + f16 accg + f32 degl[128] + f32 degg[128]

typedef __attribute__((ext_vector_type(8))) _Float16 half8;
typedef __attribute__((ext_vector_type(4))) _Float16 half4;
typedef __attribute__((ext_vector_type(4))) float f32x4;

using gas_ptr = const __attribute__((address_space(1))) void*;
using las_ptr = __attribute__((address_space(3))) void*;

__device__ __forceinline__ f32x4 mfma_16x16x32(half8 a, half8 b, f32x4 c) {
    return __builtin_amdgcn_mfma_f32_16x16x32_f16(a, b, c, 0, 0, 0);
}

// ---------------- conversions ----------------
__global__ __launch_bounds__(256) void k_cvt_h(const float* __restrict__ h,
                                               _Float16* __restrict__ h16) {
    const int i = blockIdx.x * 256 + threadIdx.x;
    f32x4 v = ((const f32x4*)h)[i];
    half4 o;
    o[0] = (_Float16)v[0]; o[1] = (_Float16)v[1];
    o[2] = (_Float16)v[2]; o[3] = (_Float16)v[3];
    ((half4*)h16)[i] = o;
}

__global__ __launch_bounds__(256) void k_wt(const float* __restrict__ W0, const float* __restrict__ W1,
                                            const float* __restrict__ W2, const float* __restrict__ W3,
                                            _Float16* __restrict__ T0, _Float16* __restrict__ T1,
                                            _Float16* __restrict__ T2, _Float16* __restrict__ T3) {
    const int m = blockIdx.y;
    const float* W = m == 0 ? W0 : m == 1 ? W1 : m == 2 ? W2 : W3;
    _Float16* T    = m == 0 ? T0 : m == 1 ? T1 : m == 2 ? T2 : T3;
    const int k = blockIdx.x, j = threadIdx.x;
    T[j * ND + k] = (_Float16)W[k * ND + j];
}

// ---------------- GEMM core (projections / output) ----------------
__device__ __forceinline__ void gemm_core(const _Float16* __restrict__ A,
                                          const _Float16* __restrict__ Bt,
                                          int row0, int l16, int lg, f32x4 acc[16]) {
    #pragma unroll
    for (int i = 0; i < 16; ++i) acc[i] = (f32x4)0.0f;
    #pragma unroll
    for (int ks = 0; ks < 8; ++ks) {
        half8 a = *(const half8*)(A + (size_t)(row0 + l16) * ND + ks * 32 + lg * 8);
        #pragma unroll
        for (int ct = 0; ct < 16; ++ct) {
            half8 b = *(const half8*)(Bt + (size_t)(ct * 16 + l16) * ND + ks * 32 + lg * 8);
            acc[ct] = mfma_16x16x32(a, b, acc[ct]);
        }
    }
}

__global__ __launch_bounds__(256) void k_proj(const _Float16* __restrict__ h16,
                                              const _Float16* __restrict__ Wlt,
                                              const _Float16* __restrict__ Wgt,
                                              const _Float16* __restrict__ Wvt,
                                              _Float16* __restrict__ zn,
                                              _Float16* __restrict__ zg,
                                              _Float16* __restrict__ v16,
                                              float* __restrict__ sq) {
    const int mode = blockIdx.y;
    const _Float16* Bt = mode == 0 ? Wlt : mode == 1 ? Wgt : Wvt;
    _Float16* o16      = mode == 0 ? zn  : mode == 1 ? zg  : v16;
    const int w = threadIdx.x >> 6, l = threadIdx.x & 63;
    const int l16 = l & 15, lg = l >> 4;
    const int row0 = blockIdx.x * 64 + w * 16;
    f32x4 acc[16];
    gemm_core(h16, Bt, row0, l16, lg, acc);

    if (mode == 2) {
        #pragma unroll
        for (int ct = 0; ct < 16; ++ct)
            #pragma unroll
            for (int r = 0; r < 4; ++r)
                o16[(size_t)(row0 + lg * 4 + r) * ND + ct * 16 + l16] = (_Float16)acc[ct][r];
        return;
    }
    float n2[4] = {0.f, 0.f, 0.f, 0.f};
    #pragma unroll
    for (int ct = 0; ct < 16; ++ct)
        #pragma unroll
        for (int r = 0; r < 4; ++r) n2[r] += acc[ct][r] * acc[ct][r];
    #pragma unroll
    for (int m = 1; m < 16; m <<= 1) {
        #pragma unroll
        for (int r = 0; r < 4; ++r) n2[r] += __shfl_xor(n2[r], m);
    }
    if (mode == 0) {
        float ri[4];
        #pragma unroll
        for (int r = 0; r < 4; ++r) ri[r] = 1.0f / fmaxf(sqrtf(n2[r]), 1e-8f);
        #pragma unroll
        for (int ct = 0; ct < 16; ++ct)
            #pragma unroll
            for (int r = 0; r < 4; ++r)
                o16[(size_t)(row0 + lg * 4 + r) * ND + ct * 16 + l16] =
                    (_Float16)(acc[ct][r] * ri[r]);
    } else {
        #pragma unroll
        for (int ct = 0; ct < 16; ++ct)
            #pragma unroll
            for (int r = 0; r < 4; ++r)
                o16[(size_t)(row0 + lg * 4 + r) * ND + ct * 16 + l16] = (_Float16)acc[ct][r];
        if (l16 == 0) {
            #pragma unroll
            for (int r = 0; r < 4; ++r) sq[row0 + lg * 4 + r] = n2[r];
        }
    }
}

// v16 [b][n][d] -> vT [b][d][n]
__global__ __launch_bounds__(256) void k_tr(const _Float16* __restrict__ v16,
                                            _Float16* __restrict__ vT) {
    __shared__ _Float16 t[64][72];
    const int b = blockIdx.z, n0 = blockIdx.x * 64, d0 = blockIdx.y * 64;
    const int tj = threadIdx.x & 63, ti = threadIdx.x >> 6;
    #pragma unroll
    for (int i = 0; i < 16; ++i)
        t[ti + i * 4][tj] = v16[(size_t)(b * NN + n0 + ti + i * 4) * ND + d0 + tj];
    __syncthreads();
    #pragma unroll
    for (int i = 0; i < 16; ++i)
        vT[(size_t)(b * ND + d0 + ti + i * 4) * NN + n0 + tj] = t[tj][ti + i * 4];
}

// ---------------- fused dual-adjacency pass, BM=128, 8 waves, split-K ----------------
// Scores: wave w owns q-rows [t*128+w*16, +16). PV: wave (wq=w>>2, wd=w&3) owns
// q [wq*64,+64) x d [wd*64,+64). Keys double-buffered in LDS (XOR-swizzled src),
// P packed one row/q: bytes 0-63 = Pl, 64-127 = Pg, XOR-swizzled.
// Pipeline: stage(kt+1)->other buf + vr(kt) + sqk(kt) all issued at tile top;
// drained at barrier A after the scores phase (~full L3 latency of cover).
__global__ __launch_bounds__(512, 2) void k_fused_split(
        const _Float16* __restrict__ zn, const _Float16* __restrict__ zg,
        const _Float16* __restrict__ vT, const float* __restrict__ sqg,
        char* __restrict__ part, int nchunk) {
    const int item = blockIdx.x;
    const int t = 31 - item / nchunk;        // long chunks dispatched first
    const int c = item % nchunk;
    const int b = blockIdx.y;
    const int ntt = 4 * (t + 1);             // 32-key tiles covering causal range
    const int len = (ntt + nchunk - 1) / nchunk;
    const int kt0 = c * len;
    const int ktE = (kt0 + len < ntt) ? (kt0 + len) : ntt;
    if (kt0 >= ktE) return;

    const int w = threadIdx.x >> 6, lane = threadIdx.x & 63;
    const int l16 = lane & 15, lg = lane >> 4;
    const int wq = w >> 2, wd = w & 3;

    __shared__ char keys[2][2][16384];       // [buf][mat][32 rows x 512B]
    __shared__ char P[128 * 128];            // packed: row q, Pl @0-63, Pg @64-127

    const char* znb = (const char*)(zn + (size_t)b * NN * ND);
    const char* zgb = (const char*)(zg + (size_t)b * NN * ND);
    const _Float16* vTb = vT + (size_t)b * ND * NN;
    const float*    sqb = sqg + (size_t)b * NN;

    const int q0w = t * 128 + w * 16;

    // hoisted q-side fragments (16 q-rows per wave, full K=256)
    half8 aql[8], aqg[8];
    #pragma unroll
    for (int ks = 0; ks < 8; ++ks) {
        aql[ks] = *(const half8*)(znb + (size_t)(q0w + l16) * 512 + ks * 64 + lg * 16);
        aqg[ks] = *(const half8*)(zgb + (size_t)(q0w + l16) * 512 + ks * 64 + lg * 16);
    }
    f32x4 sqq = *(const f32x4*)(sqb + q0w + lg * 4);

    f32x4 accl[4][4], accg[4][4];
    #pragma unroll
    for (int i = 0; i < 4; ++i)
        #pragma unroll
        for (int j = 0; j < 4; ++j) { accl[i][j] = (f32x4)0.f; accg[i][j] = (f32x4)0.f; }
    float degl[4] = {0.f, 0.f, 0.f, 0.f}, degg[4] = {0.f, 0.f, 0.f, 0.f};
    half8 vr[4];

    auto stage = [&](int kt_, int bufi) {
        const size_t gk = (size_t)kt_ * 32 * 512;
        #pragma unroll
        for (int m = 0; m < 2; ++m) {
            const char* gb = (m ? zgb : znb) + gk;
            char* lb = &keys[bufi][m][0] + w * 2048;
            #pragma unroll
            for (int i = 0; i < 2; ++i) {
                const int off = w * 2048 + i * 1024 + lane * 16;
                const int row = off >> 9, x = off & 511;
                __builtin_amdgcn_global_load_lds(
                    (gas_ptr)(gb + row * 512 + (x ^ ((row & 7) << 4))),
                    (las_ptr)(lb + i * 1024), 16, 0, 0);
            }
        }
    };

    stage(kt0, 0);
    __syncthreads();                          // drain prologue stage
    int cur = 0;

    for (int kt = kt0; kt < ktE; ++kt) {
        const int k0 = kt * 32;
        // ---- tile top: issue next stage + this tile's V fragments + sq(keys)
        if (kt + 1 < ktE) stage(kt + 1, cur ^ 1);
        #pragma unroll
        for (int ds = 0; ds < 4; ++ds)
            vr[ds] = *(const half8*)(vTb + (size_t)(wd * 64 + ds * 16 + l16) * NN + k0 + lg * 8);
        const float sqk0 = sqb[k0 + l16], sqk1 = sqb[k0 + 16 + l16];

        // ---- scores from keys[cur] (2 key sub-tiles of 16)
        #pragma unroll
        for (int kk = 0; kk < 2; ++kk) {
            f32x4 sl = (f32x4)0.f, sg = (f32x4)0.f;
            const int krl = kk * 16 + l16;
            const int swz = (krl & 7) << 4;
            #pragma unroll
            for (int ks = 0; ks < 8; ++ks) {
                const int cb = (ks * 64 + lg * 16) ^ swz;
                half8 bl = *(const half8*)(&keys[cur][0][0] + krl * 512 + cb);
                sl = mfma_16x16x32(aql[ks], bl, sl);
                half8 bg = *(const half8*)(&keys[cur][1][0] + krl * 512 + cb);
                sg = mfma_16x16x32(aqg[ks], bg, sg);
            }
            const int krow = k0 + krl;
            const float sqkv = kk ? sqk1 : sqk0;
            #pragma unroll
            for (int r = 0; r < 4; ++r) {
                const int q = q0w + lg * 4 + r;
                const bool msk = krow < q;                     // causal + zero-diag
                float al = msk ? fmaxf(sl[r], 0.f) : 0.f;      // cosine adjacency
                float d2 = fmaxf(sqq[r] + sqkv - 2.f * sg[r], 0.f);
                float ag = msk ? __expf(-0.5f * d2) : 0.f;     // RBF adjacency
                degl[r] += al; degg[r] += ag;
                const int prow = w * 16 + lg * 4 + r;
                const int psw = (prow & 7) << 4;
                *(_Float16*)(&P[0] + prow * 128 + ((krl * 2) ^ psw)) = (_Float16)al;
                *(_Float16*)(&P[0] + prow * 128 + ((64 + krl * 2) ^ psw)) = (_Float16)ag;
            }
        }
        __syncthreads();   // barrier A: P visible; drains stage(kt+1)+vr+sqk (issued ~1.3K cyc ago)
        // ---- PV: wave covers q [wq*64,+64) x d [wd*64,+64), K=32 in one step
        #pragma unroll
        for (int qs = 0; qs < 4; ++qs) {
            const int prow = wq * 64 + qs * 16 + l16;
            const int psw = (prow & 7) << 4;
            half8 pa = *(const half8*)(&P[0] + prow * 128 + ((lg * 16) ^ psw));
            half8 pb = *(const half8*)(&P[0] + prow * 128 + ((64 + lg * 16) ^ psw));
            #pragma unroll
            for (int ds = 0; ds < 4; ++ds) {
                accl[qs][ds] = mfma_16x16x32(pa, vr[ds], accl[qs][ds]);
                accg[qs][ds] = mfma_16x16x32(pb, vr[ds], accg[qs][ds]);
            }
        }
        __syncthreads();   // barrier B: P reads done before next tile's P writes
        cur ^= 1;
    }

    // ---- write partial accumulators (f16) + degrees (f32)
    char* slot = part + (size_t)((b * 32 + t) * nchunk + c) * SLOT_B;
    #pragma unroll
    for (int qs = 0; qs < 4; ++qs)
        #pragma unroll
        for (int ds = 0; ds < 4; ++ds)
            #pragma unroll
            for (int r = 0; r < 4; ++r) {
                const int row = wq * 64 + qs * 16 + lg * 4 + r;
                const int col = wd * 64 + ds * 16 + l16;
                *(_Float16*)(slot + (size_t)(row * 256 + col) * 2) = (_Float16)accl[qs][ds][r];
                *(_Float16*)(slot + 65536 + (size_t)(row * 256 + col) * 2) = (_Float16)accg[qs][ds][r];
            }
    #pragma unroll
    for (int m = 1; m < 16; m <<= 1) {
        #pragma unroll
        for (int r = 0; r < 4; ++r) {
            degl[r] += __shfl_xor(degl[r], m);
            degg[r] += __shfl_xor(degg[r], m);
        }
    }
    if (l16 == 0) {
        #pragma unroll
        for (int r = 0; r < 4; ++r) {
            *(float*)(slot + 131072 + (size_t)(w * 16 + lg * 4 + r) * 4) = degl[r];
            *(float*)(slot + 131584 + (size_t)(w * 16 + lg * 4 + r) * 4) = degg[r];
        }
    }
}

// ---------------- combine partials: sum, normalize, emit ot (f16) ----------------
__global__ __launch_bounds__(256) void k_combine(const char* __restrict__ part,
                                                 _Float16* __restrict__ ot, int nchunk) {
    const int bx = blockIdx.x;               // 32 q-tiles x 4 col-chunks
    const int t = bx >> 2, cc = bx & 3, b = blockIdx.y;
    const int ntt = 4 * (t + 1);
    const int len = (ntt + nchunk - 1) / nchunk;
    const int nact = (ntt + len - 1) / len;
    const char* s0 = part + (size_t)((b * 32 + t) * nchunk) * SLOT_B;
    __shared__ float rl[128], rg[128];
    if (threadIdx.x < 128) {
        float dl = 0.f, dg = 0.f;
        for (int c2 = 0; c2 < nact; ++c2) {
            dl += *(const float*)(s0 + (size_t)c2 * SLOT_B + 131072 + threadIdx.x * 4);
            dg += *(const float*)(s0 + (size_t)c2 * SLOT_B + 131584 + threadIdx.x * 4);
        }
        rl[threadIdx.x] = 0.9f / fmaxf(dl, 1e-8f);     // w_l = 1 - T_WAKE
        rg[threadIdx.x] = 0.1f / fmaxf(dg, 1e-8f);     // w_g = T_WAKE
    }
    __syncthreads();
    #pragma unroll
    for (int j = 0; j < 4; ++j) {
        const int flat = j * 2048 + threadIdx.x * 8;   // 8192 f16 in this col-chunk
        const int row = flat >> 6, col = flat & 63;
        const size_t eoff = (size_t)(row * 256 + cc * 64 + col) * 2;
        float s_l[8] = {0,0,0,0,0,0,0,0}, s_g[8] = {0,0,0,0,0,0,0,0};
        for (int c2 = 0; c2 < nact; ++c2) {
            half8 xl = *(const half8*)(s0 + (size_t)c2 * SLOT_B + eoff);
            half8 xg = *(const half8*)(s0 + (size_t)c2 * SLOT_B + 65536 + eoff);
            #pragma unroll
            for (int k = 0; k < 8; ++k) { s_l[k] += (float)xl[k]; s_g[k] += (float)xg[k]; }
        }
        half8 o;
        #pragma unroll
        for (int k = 0; k < 8; ++k)
            o[k] = (_Float16)(rl[row] * s_l[k] + rg[row] * s_g[k]);
        *(half8*)(ot + (size_t)(b * NN + t * 128 + row) * ND + cc * 64 + col) = o;
    }
}

// ---------------- final @ Wo ----------------
__global__ __launch_bounds__(256) void k_out(const _Float16* __restrict__ ot,
                                             const _Float16* __restrict__ Wot,
                                             float* __restrict__ out) {
    const int w = threadIdx.x >> 6, l = threadIdx.x & 63;
    const int l16 = l & 15, lg = l >> 4;
    const int row0 = blockIdx.x * 64 + w * 16;
    f32x4 acc[16];
    gemm_core(ot, Wot, row0, l16, lg, acc);
    #pragma unroll
    for (int ct = 0; ct < 16; ++ct)
        #pragma unroll
        for (int r = 0; r < 4; ++r)
            out[(size_t)(row0 + lg * 4 + r) * ND + ct * 16 + l16] = acc[ct][r];
}

extern "C" void kernel_launch(void* const* d_in, const int* in_sizes, int n_in,
                              void* d_out, int out_size, void* d_ws, size_t ws_size,
                              hipStream_t stream) {
    const float* h  = (const float*)d_in[0];
    const float* Wl = (const float*)d_in[2];
    const float* Wg = (const float*)d_in[3];
    const float* Wv = (const float*)d_in[4];
    const float* Wo = (const float*)d_in[5];
    float* out = (float*)d_out;

    uint8_t* base = (uint8_t*)d_ws;
    size_t off = 0;
    auto alloc = [&](size_t bytes) -> void* {
        void* r = base + off;
        off = (off + bytes + 255) & ~(size_t)255;
        return r;
    };
    const size_t bnd = (size_t)NB * NN * ND;
    _Float16* h16 = (_Float16*)alloc(bnd * 2);
    _Float16* Wlt = (_Float16*)alloc(ND * ND * 2);
    _Float16* Wgt = (_Float16*)alloc(ND * ND * 2);
    _Float16* Wvt = (_Float16*)alloc(ND * ND * 2);
    _Float16* Wot = (_Float16*)alloc(ND * ND * 2);
    _Float16* zn  = (_Float16*)alloc(bnd * 2);
    _Float16* zg  = (_Float16*)alloc(bnd * 2);
    _Float16* v16 = (_Float16*)alloc(bnd * 2);
    _Float16* vT  = (_Float16*)alloc(bnd * 2);
    _Float16* ot  = (_Float16*)alloc(bnd * 2);
    float*    sq  = (float*)alloc((size_t)NB * NN * 4);

    // split-K partial buffer (adaptive to ws_size)
    int nchunk = 8;
    while (nchunk > 1 &&
           off + (size_t)NB * 32 * nchunk * SLOT_B > ws_size)
        nchunk >>= 1;
    char* part = (char*)alloc((size_t)NB * 32 * nchunk * SLOT_B);

    k_cvt_h<<<bnd / 4 / 256, 256, 0, stream>>>(h, h16);
    k_wt<<<dim3(ND, 4), 256, 0, stream>>>(Wl, Wg, Wv, Wo, Wlt, Wgt, Wvt, Wot);
    k_proj<<<dim3(NB * NN / 64, 3), 256, 0, stream>>>(h16, Wlt, Wgt, Wvt, zn, zg, v16, sq);
    k_tr<<<dim3(NN / 64, ND / 64, NB), 256, 0, stream>>>(v16, vT);
    k_fused_split<<<dim3(32 * nchunk, NB), 512, 0, stream>>>(zn, zg, vT, sq, part, nchunk);
    k_combine<<<dim3(128, NB), 256, 0, stream>>>(part, ot, nchunk);
    k_out<<<NB * NN / 64, 256, 0, stream>>>(ot, Wot, out);
}

// Round 4
// 191.645 us; speedup vs baseline: 6.7476x; 1.2256x over previous
//
#include <hip/hip_runtime.h>
#include <cstdint>
#include <cstddef>

#define NB 2
#define NN 4096
#define ND 256
#define SLOT_B 132096   // bytes/partial slot: f16 accl[128][256] + f16 accg + f32 degl[128] + f32 degg[128]

typedef __attribute__((ext_vector_type(8))) _Float16 half8;
typedef __attribute__((ext_vector_type(4))) _Float16 half4;
typedef __attribute__((ext_vector_type(4))) float f32x4;

using gas_ptr = const __attribute__((address_space(1))) void*;
using las_ptr = __attribute__((address_space(3))) void*;

__device__ __forceinline__ f32x4 mfma_16x16x32(half8 a, half8 b, f32x4 c) {
    return __builtin_amdgcn_mfma_f32_16x16x32_f16(a, b, c, 0, 0, 0);
}

// ---------------- conversions ----------------
__global__ __launch_bounds__(256) void k_cvt_h(const float* __restrict__ h,
                                               _Float16* __restrict__ h16) {
    const int i = blockIdx.x * 256 + threadIdx.x;
    f32x4 v = ((const f32x4*)h)[i];
    half4 o;
    o[0] = (_Float16)v[0]; o[1] = (_Float16)v[1];
    o[2] = (_Float16)v[2]; o[3] = (_Float16)v[3];
    ((half4*)h16)[i] = o;
}

__global__ __launch_bounds__(256) void k_wt(const float* __restrict__ W0, const float* __restrict__ W1,
                                            const float* __restrict__ W2, const float* __restrict__ W3,
                                            _Float16* __restrict__ T0, _Float16* __restrict__ T1,
                                            _Float16* __restrict__ T2, _Float16* __restrict__ T3) {
    const int m = blockIdx.y;
    const float* W = m == 0 ? W0 : m == 1 ? W1 : m == 2 ? W2 : W3;
    _Float16* T    = m == 0 ? T0 : m == 1 ? T1 : m == 2 ? T2 : T3;
    const int k = blockIdx.x, j = threadIdx.x;
    T[j * ND + k] = (_Float16)W[k * ND + j];
}

// ---------------- GEMM core (projections / output) ----------------
__device__ __forceinline__ void gemm_core(const _Float16* __restrict__ A,
                                          const _Float16* __restrict__ Bt,
                                          int row0, int l16, int lg, f32x4 acc[16]) {
    #pragma unroll
    for (int i = 0; i < 16; ++i) acc[i] = (f32x4)0.0f;
    #pragma unroll
    for (int ks = 0; ks < 8; ++ks) {
        half8 a = *(const half8*)(A + (size_t)(row0 + l16) * ND + ks * 32 + lg * 8);
        #pragma unroll
        for (int ct = 0; ct < 16; ++ct) {
            half8 b = *(const half8*)(Bt + (size_t)(ct * 16 + l16) * ND + ks * 32 + lg * 8);
            acc[ct] = mfma_16x16x32(a, b, acc[ct]);
        }
    }
}

__global__ __launch_bounds__(256) void k_proj(const _Float16* __restrict__ h16,
                                              const _Float16* __restrict__ Wlt,
                                              const _Float16* __restrict__ Wgt,
                                              const _Float16* __restrict__ Wvt,
                                              _Float16* __restrict__ zn,
                                              _Float16* __restrict__ zg,
                                              _Float16* __restrict__ v16,
                                              float* __restrict__ sq) {
    const int mode = blockIdx.y;
    const _Float16* Bt = mode == 0 ? Wlt : mode == 1 ? Wgt : Wvt;
    _Float16* o16      = mode == 0 ? zn  : mode == 1 ? zg  : v16;
    const int w = threadIdx.x >> 6, l = threadIdx.x & 63;
    const int l16 = l & 15, lg = l >> 4;
    const int row0 = blockIdx.x * 64 + w * 16;
    f32x4 acc[16];
    gemm_core(h16, Bt, row0, l16, lg, acc);

    if (mode == 2) {
        #pragma unroll
        for (int ct = 0; ct < 16; ++ct)
            #pragma unroll
            for (int r = 0; r < 4; ++r)
                o16[(size_t)(row0 + lg * 4 + r) * ND + ct * 16 + l16] = (_Float16)acc[ct][r];
        return;
    }
    float n2[4] = {0.f, 0.f, 0.f, 0.f};
    #pragma unroll
    for (int ct = 0; ct < 16; ++ct)
        #pragma unroll
        for (int r = 0; r < 4; ++r) n2[r] += acc[ct][r] * acc[ct][r];
    #pragma unroll
    for (int m = 1; m < 16; m <<= 1) {
        #pragma unroll
        for (int r = 0; r < 4; ++r) n2[r] += __shfl_xor(n2[r], m);
    }
    if (mode == 0) {
        float ri[4];
        #pragma unroll
        for (int r = 0; r < 4; ++r) ri[r] = 1.0f / fmaxf(sqrtf(n2[r]), 1e-8f);
        #pragma unroll
        for (int ct = 0; ct < 16; ++ct)
            #pragma unroll
            for (int r = 0; r < 4; ++r)
                o16[(size_t)(row0 + lg * 4 + r) * ND + ct * 16 + l16] =
                    (_Float16)(acc[ct][r] * ri[r]);
    } else {
        #pragma unroll
        for (int ct = 0; ct < 16; ++ct)
            #pragma unroll
            for (int r = 0; r < 4; ++r)
                o16[(size_t)(row0 + lg * 4 + r) * ND + ct * 16 + l16] = (_Float16)acc[ct][r];
        if (l16 == 0) {
            #pragma unroll
            for (int r = 0; r < 4; ++r) sq[row0 + lg * 4 + r] = n2[r];
        }
    }
}

// v16 [b][n][d] -> vT [b][d][n]
__global__ __launch_bounds__(256) void k_tr(const _Float16* __restrict__ v16,
                                            _Float16* __restrict__ vT) {
    __shared__ _Float16 t[64][72];
    const int b = blockIdx.z, n0 = blockIdx.x * 64, d0 = blockIdx.y * 64;
    const int tj = threadIdx.x & 63, ti = threadIdx.x >> 6;
    #pragma unroll
    for (int i = 0; i < 16; ++i)
        t[ti + i * 4][tj] = v16[(size_t)(b * NN + n0 + ti + i * 4) * ND + d0 + tj];
    __syncthreads();
    #pragma unroll
    for (int i = 0; i < 16; ++i)
        vT[(size_t)(b * ND + d0 + ti + i * 4) * NN + n0 + tj] = t[tj][ti + i * 4];
}

// ---------------- fused dual-adjacency pass, BM=128, 8 waves, split-K ----------------
// S^T orientation: scores computed as mfma(A=key-frag, B=Q-frag) so each lane
// holds q = l16 (col) and 4 row-contiguous keys (lg*4+r) -> b64 P-writes,
// scalar per-lane degree. One barrier per key-tile: P double-buffered, so
// PV(kt) overlaps scores(kt+1); keys double-buffered with stage(kt+1) issued
// at tile top (a full scores-phase of latency cover before the barrier drain).
__global__ __launch_bounds__(512, 2) void k_fused_split(
        const _Float16* __restrict__ zn, const _Float16* __restrict__ zg,
        const _Float16* __restrict__ vT, const float* __restrict__ sqg,
        char* __restrict__ part, int nchunk) {
    const int item = blockIdx.x;
    const int t = 31 - item / nchunk;        // long chunks dispatched first
    const int c = item % nchunk;
    const int b = blockIdx.y;
    const int ntt = 4 * (t + 1);             // 32-key tiles covering causal range
    const int len = (ntt + nchunk - 1) / nchunk;
    const int kt0 = c * len;
    const int ktE = (kt0 + len < ntt) ? (kt0 + len) : ntt;
    if (kt0 >= ktE) return;

    const int w = threadIdx.x >> 6, lane = threadIdx.x & 63;
    const int l16 = lane & 15, lg = lane >> 4;
    const int wq = w >> 2, wd = w & 3;

    __shared__ char keys[2][2][16384];       // [buf][mat][32 rows x 512B]
    __shared__ char P[2][16384];             // [buf][row q: Pl @0-63 | Pg @64-127]

    const char* znb = (const char*)(zn + (size_t)b * NN * ND);
    const char* zgb = (const char*)(zg + (size_t)b * NN * ND);
    const _Float16* vTb = vT + (size_t)b * ND * NN;
    const float*    sqb = sqg + (size_t)b * NN;

    const int q0w = t * 128 + w * 16;
    const int q = q0w + l16;                 // this lane's q-row (scores role)

    // hoisted q-side fragments (B-operand for S^T): Q[q][ks*32 + lg*8 + e]
    half8 aql[8], aqg[8];
    #pragma unroll
    for (int ks = 0; ks < 8; ++ks) {
        aql[ks] = *(const half8*)(znb + (size_t)q * 512 + ks * 64 + lg * 16);
        aqg[ks] = *(const half8*)(zgb + (size_t)q * 512 + ks * 64 + lg * 16);
    }
    const float sqq = sqb[q];

    f32x4 accl[4][4], accg[4][4];
    #pragma unroll
    for (int i = 0; i < 4; ++i)
        #pragma unroll
        for (int j = 0; j < 4; ++j) { accl[i][j] = (f32x4)0.f; accg[i][j] = (f32x4)0.f; }
    float dl = 0.f, dg = 0.f;
    half8 vr[4];

    auto stage = [&](int kt_, int bufi) {
        const size_t gk = (size_t)kt_ * 32 * 512;
        #pragma unroll
        for (int m = 0; m < 2; ++m) {
            const char* gb = (m ? zgb : znb) + gk;
            char* lb = &keys[bufi][m][0];
            #pragma unroll
            for (int i = 0; i < 2; ++i) {
                const int off = w * 2048 + i * 1024 + lane * 16;
                const int row = off >> 9, x = off & 511;
                __builtin_amdgcn_global_load_lds(
                    (gas_ptr)(gb + row * 512 + (x ^ ((row & 7) << 4))),
                    (las_ptr)(lb + w * 2048 + i * 1024), 16, 0, 0);
            }
        }
    };

    stage(kt0, 0);
    __syncthreads();                          // drain prologue stage
    int cur = 0;

    for (int kt = kt0; kt < ktE; ++kt) {
        const int k0 = kt * 32;
        // ---- tile top: issue next stage + this tile's V fragments
        if (kt + 1 < ktE) stage(kt + 1, cur ^ 1);
        #pragma unroll
        for (int ds = 0; ds < 4; ++ds)
            vr[ds] = *(const half8*)(vTb + (size_t)(wd * 64 + ds * 16 + l16) * NN + k0 + lg * 8);

        // ---- scores (S^T): 2 key sub-tiles of 16 rows
        #pragma unroll
        for (int kk = 0; kk < 2; ++kk) {
            f32x4 sl = (f32x4)0.f, sg = (f32x4)0.f;
            const int arow = kk * 16 + l16;            // key row fed as A
            const int swz = (arow & 7) << 4;
            #pragma unroll
            for (int ks = 0; ks < 8; ++ks) {
                const int cb = (ks * 64 + lg * 16) ^ swz;
                half8 kal = *(const half8*)(&keys[cur][0][0] + arow * 512 + cb);
                sl = mfma_16x16x32(kal, aql[ks], sl);  // A=keys, B=Q -> S^T
                half8 kag = *(const half8*)(&keys[cur][1][0] + arow * 512 + cb);
                sg = mfma_16x16x32(kag, aqg[ks], sg);
            }
            // lane holds S^T[k = kbase + r][q], r=0..3 row-contiguous keys
            const int kbase = k0 + kk * 16 + lg * 4;
            const f32x4 sqk = *(const f32x4*)(sqb + kbase);
            const int m0 = q - kbase;                  // r < m0 -> unmasked (k < q)
            half4 hl, hg;
            #pragma unroll
            for (int r = 0; r < 4; ++r) {
                const bool msk = r < m0;               // causal + zero-diag
                float pl = msk ? fmaxf(sl[r], 0.f) : 0.f;
                float pg = msk ? __expf(-0.5f * (sqq + sqk[r] - 2.f * sg[r])) : 0.f;
                dl += pl; dg += pg;
                hl[r] = (_Float16)pl; hg[r] = (_Float16)pg;
            }
            const int prow = w * 16 + l16;
            const int psw = (prow & 7) << 4;
            *(half4*)(&P[cur][0] + prow * 128 + ((kk * 32 + lg * 8) ^ psw)) = hl;
            *(half4*)(&P[cur][0] + prow * 128 + ((64 + kk * 32 + lg * 8) ^ psw)) = hg;
        }
        __syncthreads();   // the ONLY barrier: drains stage(kt+1)+vr, publishes P[cur]

        // ---- PV: wave covers q [wq*64,+64) x d [wd*64,+64); overlaps next scores
        __builtin_amdgcn_s_setprio(1);
        #pragma unroll
        for (int qs = 0; qs < 4; ++qs) {
            const int prow = wq * 64 + qs * 16 + l16;
            const int psw = (prow & 7) << 4;
            half8 pa = *(const half8*)(&P[cur][0] + prow * 128 + ((lg * 16) ^ psw));
            half8 pb = *(const half8*)(&P[cur][0] + prow * 128 + ((64 + lg * 16) ^ psw));
            #pragma unroll
            for (int ds = 0; ds < 4; ++ds) {
                accl[qs][ds] = mfma_16x16x32(pa, vr[ds], accl[qs][ds]);
                accg[qs][ds] = mfma_16x16x32(pb, vr[ds], accg[qs][ds]);
            }
        }
        __builtin_amdgcn_s_setprio(0);
        cur ^= 1;
    }

    // ---- write partial accumulators (f16) + degrees (f32)
    char* slot = part + (size_t)((b * 32 + t) * nchunk + c) * SLOT_B;
    #pragma unroll
    for (int qs = 0; qs < 4; ++qs)
        #pragma unroll
        for (int ds = 0; ds < 4; ++ds)
            #pragma unroll
            for (int r = 0; r < 4; ++r) {
                const int row = wq * 64 + qs * 16 + lg * 4 + r;
                const int col = wd * 64 + ds * 16 + l16;
                *(_Float16*)(slot + (size_t)(row * 256 + col) * 2) = (_Float16)accl[qs][ds][r];
                *(_Float16*)(slot + 65536 + (size_t)(row * 256 + col) * 2) = (_Float16)accg[qs][ds][r];
            }
    dl += __shfl_xor(dl, 16); dl += __shfl_xor(dl, 32);
    dg += __shfl_xor(dg, 16); dg += __shfl_xor(dg, 32);
    if (lg == 0) {
        *(float*)(slot + 131072 + (size_t)(w * 16 + l16) * 4) = dl;
        *(float*)(slot + 131584 + (size_t)(w * 16 + l16) * 4) = dg;
    }
}

// ---------------- combine partials: sum, normalize, emit ot (f16) ----------------
__global__ __launch_bounds__(256) void k_combine(const char* __restrict__ part,
                                                 _Float16* __restrict__ ot, int nchunk) {
    const int bx = blockIdx.x;               // 32 q-tiles x 4 col-chunks
    const int t = bx >> 2, cc = bx & 3, b = blockIdx.y;
    const int ntt = 4 * (t + 1);
    const int len = (ntt + nchunk - 1) / nchunk;
    const int nact = (ntt + len - 1) / len;
    const char* s0 = part + (size_t)((b * 32 + t) * nchunk) * SLOT_B;
    __shared__ float rl[128], rg[128];
    if (threadIdx.x < 128) {
        float dl = 0.f, dg = 0.f;
        for (int c2 = 0; c2 < nact; ++c2) {
            dl += *(const float*)(s0 + (size_t)c2 * SLOT_B + 131072 + threadIdx.x * 4);
            dg += *(const float*)(s0 + (size_t)c2 * SLOT_B + 131584 + threadIdx.x * 4);
        }
        rl[threadIdx.x] = 0.9f / fmaxf(dl, 1e-8f);     // w_l = 1 - T_WAKE
        rg[threadIdx.x] = 0.1f / fmaxf(dg, 1e-8f);     // w_g = T_WAKE
    }
    __syncthreads();
    #pragma unroll
    for (int j = 0; j < 4; ++j) {
        const int flat = j * 2048 + threadIdx.x * 8;   // 8192 f16 in this col-chunk
        const int row = flat >> 6, col = flat & 63;
        const size_t eoff = (size_t)(row * 256 + cc * 64 + col) * 2;
        float s_l[8] = {0,0,0,0,0,0,0,0}, s_g[8] = {0,0,0,0,0,0,0,0};
        for (int c2 = 0; c2 < nact; ++c2) {
            half8 xl = *(const half8*)(s0 + (size_t)c2 * SLOT_B + eoff);
            half8 xg = *(const half8*)(s0 + (size_t)c2 * SLOT_B + 65536 + eoff);
            #pragma unroll
            for (int k = 0; k < 8; ++k) { s_l[k] += (float)xl[k]; s_g[k] += (float)xg[k]; }
        }
        half8 o;
        #pragma unroll
        for (int k = 0; k < 8; ++k)
            o[k] = (_Float16)(rl[row] * s_l[k] + rg[row] * s_g[k]);
        *(half8*)(ot + (size_t)(b * NN + t * 128 + row) * ND + cc * 64 + col) = o;
    }
}

// ---------------- final @ Wo ----------------
__global__ __launch_bounds__(256) void k_out(const _Float16* __restrict__ ot,
                                             const _Float16* __restrict__ Wot,
                                             float* __restrict__ out) {
    const int w = threadIdx.x >> 6, l = threadIdx.x & 63;
    const int l16 = l & 15, lg = l >> 4;
    const int row0 = blockIdx.x * 64 + w * 16;
    f32x4 acc[16];
    gemm_core(ot, Wot, row0, l16, lg, acc);
    #pragma unroll
    for (int ct = 0; ct < 16; ++ct)
        #pragma unroll
        for (int r = 0; r < 4; ++r)
            out[(size_t)(row0 + lg * 4 + r) * ND + ct * 16 + l16] = acc[ct][r];
}

extern "C" void kernel_launch(void* const* d_in, const int* in_sizes, int n_in,
                              void* d_out, int out_size, void* d_ws, size_t ws_size,
                              hipStream_t stream) {
    const float* h  = (const float*)d_in[0];
    const float* Wl = (const float*)d_in[2];
    const float* Wg = (const float*)d_in[3];
    const float* Wv = (const float*)d_in[4];
    const float* Wo = (const float*)d_in[5];
    float* out = (float*)d_out;

    uint8_t* base = (uint8_t*)d_ws;
    size_t off = 0;
    auto alloc = [&](size_t bytes) -> void* {
        void* r = base + off;
        off = (off + bytes + 255) & ~(size_t)255;
        return r;
    };
    const size_t bnd = (size_t)NB * NN * ND;
    _Float16* h16 = (_Float16*)alloc(bnd * 2);
    _Float16* Wlt = (_Float16*)alloc(ND * ND * 2);
    _Float16* Wgt = (_Float16*)alloc(ND * ND * 2);
    _Float16* Wvt = (_Float16*)alloc(ND * ND * 2);
    _Float16* Wot = (_Float16*)alloc(ND * ND * 2);
    _Float16* zn  = (_Float16*)alloc(bnd * 2);
    _Float16* zg  = (_Float16*)alloc(bnd * 2);
    _Float16* v16 = (_Float16*)alloc(bnd * 2);
    _Float16* vT  = (_Float16*)alloc(bnd * 2);
    _Float16* ot  = (_Float16*)alloc(bnd * 2);
    float*    sq  = (float*)alloc((size_t)NB * NN * 4);

    // split-K partial buffer (adaptive to ws_size)
    int nchunk = 8;
    while (nchunk > 1 &&
           off + (size_t)NB * 32 * nchunk * SLOT_B > ws_size)
        nchunk >>= 1;
    char* part = (char*)alloc((size_t)NB * 32 * nchunk * SLOT_B);

    k_cvt_h<<<bnd / 4 / 256, 256, 0, stream>>>(h, h16);
    k_wt<<<dim3(ND, 4), 256, 0, stream>>>(Wl, Wg, Wv, Wo, Wlt, Wgt, Wvt, Wot);
    k_proj<<<dim3(NB * NN / 64, 3), 256, 0, stream>>>(h16, Wlt, Wgt, Wvt, zn, zg, v16, sq);
    k_tr<<<dim3(NN / 64, ND / 64, NB), 256, 0, stream>>>(v16, vT);
    k_fused_split<<<dim3(32 * nchunk, NB), 512, 0, stream>>>(zn, zg, vT, sq, part, nchunk);
    k_combine<<<dim3(128, NB), 256, 0, stream>>>(part, ot, nchunk);
    k_out<<<NB * NN / 64, 256, 0, stream>>>(ot, Wot, out);
}